// Round 1
// baseline (2064.939 us; speedup 1.0000x reference)
//
#include <hip/hip_runtime.h>

// ---------------------------------------------------------------------------
// GRUAgg: ragged groups -> dense [B,96,D] (timestamp-sorted, zero-padded head)
// -> 2-layer GRU (PyTorch gate order r,z,n) -> mean over 96 steps.
// B=2048, L=96, D=256, 3D=768, E=131072.
//
// Pipeline (per T-chunk of Tc steps):
//   k_xgemm(gather x via perm) -> xgA = x@W_ih0^T + b_ih0       [bf16 MFMA]
//   k_recur(layer0, W_hh0 reg/LDS-resident) -> h1buf (bf16)
//   k_xgemm(dense h1buf)       -> xgB = h1@W_ih1^T + b_ih1
//   k_recur(layer1) -> accumulate mean; last chunk writes d_out (fp32)
// ---------------------------------------------------------------------------

typedef short bh8 __attribute__((ext_vector_type(8)));   // 8 bf16 in 4 VGPRs
typedef float f4  __attribute__((ext_vector_type(4)));   // MFMA accumulator

#define NB 2048
#define LT 96
#define DF 256
#define NG 768

static __device__ __forceinline__ unsigned short f2b(float f) {
  union { float f; unsigned int u; } v; v.f = f;
  unsigned int r = v.u + 0x7fffu + ((v.u >> 16) & 1u);   // RNE
  return (unsigned short)(r >> 16);
}
static __device__ __forceinline__ float b2f(unsigned short s) {
  union { unsigned int u; float f; } v; v.u = ((unsigned int)s) << 16; return v.f;
}
static __device__ __forceinline__ float sigm(float x) { return 1.0f / (1.0f + __expf(-x)); }
static __device__ __forceinline__ float tanh_(float x) { return 2.0f / (1.0f + __expf(-2.0f * x)) - 1.0f; }

// --------------------------- group offsets/counts ---------------------------
__global__ void k_offsets(const int* __restrict__ idx, int E,
                          int* __restrict__ offs, int* __restrict__ cnt) {
  int b = blockIdx.x * blockDim.x + threadIdx.x;
  if (b >= NB) return;
  int lo = 0, hi = E;
  while (lo < hi) { int m = (lo + hi) >> 1; if (idx[m] < b) lo = m + 1; else hi = m; }
  int lb = lo;
  lo = lb; hi = E;
  while (lo < hi) { int m = (lo + hi) >> 1; if (idx[m] < b + 1) lo = m + 1; else hi = m; }
  offs[b] = lb;
  cnt[b] = lo - lb;
}

// ------------- per-group stable timestamp rank -> slot permutation ----------
// slot semantics match jnp.argsort(dense ts, stable): pads (ts=0, pos>=cnt)
// come before positive ts, after real zeros. perm[b*96+slot] = edge or -1.
__global__ void k_rank(const float* __restrict__ ts, const int* __restrict__ offs,
                       const int* __restrict__ cnt, int* __restrict__ perm) {
  __shared__ float sts[96];
  int b = blockIdx.x, j = threadIdx.x;
  int o = offs[b];
  int c = cnt[b]; if (c > 96) c = 96;
  if (j < 96) perm[b * 96 + j] = -1;
  if (j < c) sts[j] = ts[o + j];
  __syncthreads();
  if (j < c) {
    float tj = sts[j];
    int rank = 0;
    for (int k = 0; k < c; ++k) {
      float tk = sts[k];
      rank += (tk < tj) || (tk == tj && k < j);
    }
    int slot = (tj > 0.0f ? (96 - c) : 0) + rank;
    perm[b * 96 + slot] = o + j;
  }
}

// ------------- pack 4 weight matrices into MFMA B-fragment order ------------
// value(nt,kt,lane,j) = W[n][k], n = nt*16+(lane&15), k = kt*32+(lane>>4)*8+j
// layout: [mat(4)][nt(48)][kt(8)][lane(64)][j(8)] bf16
__global__ void k_packw(const float* __restrict__ w0, const float* __restrict__ w1,
                        const float* __restrict__ w2, const float* __restrict__ w3,
                        unsigned short* __restrict__ wfrag) {
  int t = blockIdx.x * blockDim.x + threadIdx.x;
  if (t >= 4 * 48 * 8 * 64) return;
  int m = t / 24576;
  int r = t % 24576;
  int nt = r / 512;
  int kt = (r / 64) & 7;
  int lane = r & 63;
  int n = nt * 16 + (lane & 15);
  int kb = kt * 32 + (lane >> 4) * 8;
  const float* W = (m == 0) ? w0 : (m == 1) ? w1 : (m == 2) ? w2 : w3;
  unsigned int o[4];
#pragma unroll
  for (int p = 0; p < 4; ++p) {
    unsigned short a = f2b(W[n * 256 + kb + 2 * p]);
    unsigned short b = f2b(W[n * 256 + kb + 2 * p + 1]);
    o[p] = (unsigned int)a | ((unsigned int)b << 16);
  }
  uint4 v; v.x = o[0]; v.y = o[1]; v.z = o[2]; v.w = o[3];
  *(uint4*)&wfrag[(size_t)t * 8] = v;
}

// --------------------------- input-projection GEMM --------------------------
// C[rows][768] = A[rows][256] @ W^T + b_ih, bf16 in/out, fp32 accum.
// amode 0: A rows gathered from x (fp32) via perm (row = tt*2048+g); -1 -> 0.
// amode 1: A = dense bf16 rows (h1buf).
// grid: (Mtiles = rows/128, 6 n-tiles of 128), block 256 (4 waves).
__launch_bounds__(256)
__global__ void k_xgemm(const float* __restrict__ Ax, const unsigned short* __restrict__ Ab,
                        int amode, const int* __restrict__ perm, int t0,
                        const unsigned short* __restrict__ wfrag, const float* __restrict__ bias,
                        unsigned short* __restrict__ Cout) {
  __shared__ __align__(16) unsigned short lA[128 * 264];  // 67584 B (reused as fp32 slab)
  __shared__ __align__(16) unsigned short lB[32768];      // 65536 B: 8 ntiles of frags
  __shared__ float lbias[128];
  __shared__ int lsrc[128];

  const int tid = threadIdx.x;
  const int mt = blockIdx.x, ntb = blockIdx.y;

  if (tid < 32) {
    f4 bv = *(const f4*)&bias[ntb * 128 + tid * 4];
    *(f4*)&lbias[tid * 4] = bv;
  }
  if (amode == 0 && tid < 128) {
    int row = mt * 128 + tid;
    int tt = row >> 11, g = row & 2047;
    lsrc[tid] = perm[g * 96 + t0 + tt];
  }
  __syncthreads();

  if (amode == 0) {
    for (int i = tid; i < 128 * 64; i += 256) {
      int row = i >> 6, c4 = i & 63;
      int src = lsrc[row];
      f4 v = {0.f, 0.f, 0.f, 0.f};
      if (src >= 0) v = *(const f4*)(Ax + (size_t)src * 256 + c4 * 4);
      unsigned int lo = (unsigned int)f2b(v.x) | ((unsigned int)f2b(v.y) << 16);
      unsigned int hi = (unsigned int)f2b(v.z) | ((unsigned int)f2b(v.w) << 16);
      uint2 u; u.x = lo; u.y = hi;
      *(uint2*)&lA[row * 264 + c4 * 4] = u;
    }
  } else {
    for (int i = tid; i < 128 * 32; i += 256) {
      int row = i >> 5, c8 = i & 31;
      uint4 v = *(const uint4*)&Ab[((size_t)mt * 128 + row) * 256 + c8 * 8];
      *(uint4*)&lA[row * 264 + c8 * 8] = v;
    }
  }
  {
    const uint4* s = (const uint4*)(wfrag + (size_t)ntb * 32768);
    uint4* d = (uint4*)lB;
    for (int i = tid; i < 4096; i += 256) d[i] = s[i];
  }
  __syncthreads();

  const int w = tid >> 6, l = tid & 63, lm = l & 15, lq = l >> 4;
  f4 acc[2][8];
#pragma unroll
  for (int i = 0; i < 2; ++i)
#pragma unroll
    for (int j = 0; j < 8; ++j) acc[i][j] = (f4){0.f, 0.f, 0.f, 0.f};

#pragma unroll
  for (int kt = 0; kt < 8; ++kt) {
    bh8 a0 = *(const bh8*)&lA[(32 * w + lm) * 264 + kt * 32 + lq * 8];
    bh8 a1 = *(const bh8*)&lA[(32 * w + 16 + lm) * 264 + kt * 32 + lq * 8];
#pragma unroll
    for (int nt = 0; nt < 8; ++nt) {
      bh8 b = *(const bh8*)&lB[((nt * 8 + kt) * 64 + l) * 8];
      acc[0][nt] = __builtin_amdgcn_mfma_f32_16x16x32_bf16(a0, b, acc[0][nt], 0, 0, 0);
      acc[1][nt] = __builtin_amdgcn_mfma_f32_16x16x32_bf16(a1, b, acc[1][nt], 0, 0, 0);
    }
  }
  __syncthreads();

  float* slab = (float*)lA;  // [128][132]
#pragma unroll
  for (int m2 = 0; m2 < 2; ++m2)
#pragma unroll
    for (int nt = 0; nt < 8; ++nt)
#pragma unroll
      for (int r = 0; r < 4; ++r)
        slab[(32 * w + 16 * m2 + 4 * lq + r) * 132 + nt * 16 + lm] =
            acc[m2][nt][r] + lbias[nt * 16 + lm];
  __syncthreads();

  {
    int row = tid >> 1, half = tid & 1;
    size_t base = ((size_t)mt * 128 + row) * NG + ntb * 128 + half * 64;
    const float* s = &slab[row * 132 + half * 64];
#pragma unroll
    for (int i = 0; i < 8; ++i) {
      f4 v0 = *(const f4*)(s + i * 8);
      f4 v1 = *(const f4*)(s + i * 8 + 4);
      uint4 o;
      o.x = (unsigned int)f2b(v0.x) | ((unsigned int)f2b(v0.y) << 16);
      o.y = (unsigned int)f2b(v0.z) | ((unsigned int)f2b(v0.w) << 16);
      o.z = (unsigned int)f2b(v1.x) | ((unsigned int)f2b(v1.y) << 16);
      o.w = (unsigned int)f2b(v1.z) | ((unsigned int)f2b(v1.w) << 16);
      *(uint4*)&Cout[base + i * 8] = o;
    }
  }
}

// ------------------------------ recurrent core ------------------------------
// 128 blocks x 1024 thr (16 waves). Block owns 16 groups (M=16).
// Wave w owns h-columns w*16..w*16+15 across all 3 gates:
//   r gate: ntile w      (B-frags in VGPRs, 32 regs)
//   z gate: ntile 16+w   (B-frags in VGPRs, 32 regs)
//   n gate: ntile 32+w   (B-frags in LDS, 128 KB)
// h kept fp32-master + bf16 copy in LDS. xg = x@W_ih^T + b_ih precomputed.
__launch_bounds__(1024)
__global__ void k_recur(const unsigned short* __restrict__ wf,  // this layer's W_hh frags
                        const float* __restrict__ bhh,
                        const unsigned short* __restrict__ xg,  // [tt*2048+g][768] bf16 (chunk)
                        int Ta, float* __restrict__ hstate, int first, int save,
                        unsigned short* __restrict__ h1out,     // layer0 out (chunk) or null
                        float* __restrict__ sumstate, float* __restrict__ outp,
                        int last, int layer) {
  __shared__ __align__(16) unsigned short lh[16 * 264];   //  8448 B bf16 h
  __shared__ __align__(16) float lhf[16 * 260];           // 16640 B fp32 h master
  __shared__ __align__(16) unsigned short lBn[65536];     // 131072 B n-gate frags

  const int tid = threadIdx.x;
  const int w = tid >> 6, l = tid & 63, lm = l & 15, lq = l >> 4;
  const int g0 = blockIdx.x * 16;
  const int col = (w << 4) + lm;

  // r,z gate B-fragments resident in VGPRs (must stay unrolled/const-indexed).
  bh8 br[8], bz[8];
#pragma unroll
  for (int kt = 0; kt < 8; ++kt) {
    br[kt] = *(const bh8*)&wf[((w * 8 + kt) * 64 + l) * 8];
    bz[kt] = *(const bh8*)&wf[(((16 + w) * 8 + kt) * 64 + l) * 8];
  }
  const float bhr = bhh[col];
  const float bhz = bhh[256 + col];
  const float bhn = bhh[512 + col];

  // stage n-gate frags (global frag elems [131072,196608)) linearly into LDS
  {
    const uint4* s = (const uint4*)(wf + 131072);
    uint4* d = (uint4*)lBn;
    for (int i = tid; i < 8192; i += 1024) d[i] = s[i];
  }
  // h init
  for (int i = tid; i < 16 * DF; i += 1024) {
    int r = i >> 8, c = i & 255;
    float hv = first ? 0.0f : hstate[(size_t)(g0 + r) * DF + c];
    lhf[r * 260 + c] = hv;
    lh[r * 264 + c] = f2b(hv);
  }
  float sums[4] = {0.f, 0.f, 0.f, 0.f};
  if (layer == 1 && !first) {
#pragma unroll
    for (int reg = 0; reg < 4; ++reg)
      sums[reg] = sumstate[(size_t)(g0 + lq * 4 + reg) * DF + col];
  }
  __syncthreads();

  for (int tt = 0; tt < Ta; ++tt) {
    // xg preactivations for this lane's 4 rows x 3 gates (issue early)
    float xr[4], xz[4], xn[4];
    {
      size_t base = ((size_t)tt * NB + g0 + lq * 4) * NG + col;
#pragma unroll
      for (int reg = 0; reg < 4; ++reg) {
        xr[reg] = b2f(xg[base + (size_t)reg * NG]);
        xz[reg] = b2f(xg[base + (size_t)reg * NG + 256]);
        xn[reg] = b2f(xg[base + (size_t)reg * NG + 512]);
      }
    }
    f4 ar = (f4){0.f, 0.f, 0.f, 0.f};
    f4 az = (f4){0.f, 0.f, 0.f, 0.f};
    f4 an = (f4){0.f, 0.f, 0.f, 0.f};
#pragma unroll
    for (int kt = 0; kt < 8; ++kt) {
      bh8 a = *(const bh8*)&lh[lm * 264 + kt * 32 + lq * 8];
      ar = __builtin_amdgcn_mfma_f32_16x16x32_bf16(a, br[kt], ar, 0, 0, 0);
      az = __builtin_amdgcn_mfma_f32_16x16x32_bf16(a, bz[kt], az, 0, 0, 0);
      bh8 bn = *(const bh8*)&lBn[((w * 8 + kt) * 64 + l) * 8];
      an = __builtin_amdgcn_mfma_f32_16x16x32_bf16(a, bn, an, 0, 0, 0);
    }
    __syncthreads();  // all waves done reading lh for this step
#pragma unroll
    for (int reg = 0; reg < 4; ++reg) {
      int row = lq * 4 + reg;
      float rr = sigm(xr[reg] + ar[reg] + bhr);
      float zz = sigm(xz[reg] + az[reg] + bhz);
      float nn = tanh_(xn[reg] + rr * (an[reg] + bhn));
      float hp = lhf[row * 260 + col];
      float hv = (1.0f - zz) * nn + zz * hp;
      lhf[row * 260 + col] = hv;
      lh[row * 264 + col] = f2b(hv);
      if (layer == 0)
        h1out[((size_t)tt * NB + g0 + row) * DF + col] = f2b(hv);
      else
        sums[reg] += hv;
    }
    __syncthreads();  // h updates visible before next step's MFMA reads
  }

  if (save) {
    for (int i = tid; i < 16 * DF; i += 1024) {
      int r = i >> 8, c = i & 255;
      hstate[(size_t)(g0 + r) * DF + c] = lhf[r * 260 + c];
    }
  }
  if (layer == 1) {
    if (last) {
#pragma unroll
      for (int reg = 0; reg < 4; ++reg)
        outp[(size_t)(g0 + lq * 4 + reg) * DF + col] = sums[reg] * (1.0f / 96.0f);
    } else {
#pragma unroll
      for (int reg = 0; reg < 4; ++reg)
        sumstate[(size_t)(g0 + lq * 4 + reg) * DF + col] = sums[reg];
    }
  }
}

// ------------------------------- host launcher ------------------------------
extern "C" void kernel_launch(void* const* d_in, const int* in_sizes, int n_in,
                              void* d_out, int out_size, void* d_ws, size_t ws_size,
                              hipStream_t stream) {
  (void)n_in; (void)out_size;
  const float* x    = (const float*)d_in[0];
  const float* ts   = (const float*)d_in[1];
  const float* wih0 = (const float*)d_in[2];
  const float* whh0 = (const float*)d_in[3];
  const float* bih0 = (const float*)d_in[4];
  const float* bhh0 = (const float*)d_in[5];
  const float* wih1 = (const float*)d_in[6];
  const float* whh1 = (const float*)d_in[7];
  const float* bih1 = (const float*)d_in[8];
  const float* bhh1 = (const float*)d_in[9];
  const int*   idx  = (const int*)d_in[10];
  float* out = (float*)d_out;
  const int E = in_sizes[0] / DF;

  char* wsb = (char*)d_ws;
  size_t off = 0;
  auto carve = [&](size_t bytes) -> char* {
    off = (off + 255) & ~(size_t)255;
    char* p = wsb + off;
    off += bytes;
    return p;
  };
  int* offs = (int*)carve((size_t)NB * 4);
  int* cntp = (int*)carve((size_t)NB * 4);
  int* perm = (int*)carve((size_t)NB * LT * 4);
  unsigned short* wfrag = (unsigned short*)carve((size_t)4 * 196608 * 2);
  float* h0s  = (float*)carve((size_t)NB * DF * 4);
  float* h1s  = (float*)carve((size_t)NB * DF * 4);
  float* sums = (float*)carve((size_t)NB * DF * 4);
  size_t fixedBytes = off;

  const size_t perT = (size_t)NB * DF * 2 + 2 * (size_t)NB * NG * 2;  // 7,340,032 B
  int Tc = 1;
  if (ws_size > fixedBytes + 4096) {
    size_t t = (ws_size - fixedBytes - 4096) / perT;
    Tc = (int)(t > 96 ? 96 : (t < 1 ? 1 : t));
  }
  unsigned short* h1buf = (unsigned short*)carve((size_t)Tc * NB * DF * 2);
  unsigned short* xgA   = (unsigned short*)carve((size_t)Tc * NB * NG * 2);
  unsigned short* xgB   = (unsigned short*)carve((size_t)Tc * NB * NG * 2);

  k_offsets<<<8, 256, 0, stream>>>(idx, E, offs, cntp);
  k_rank<<<NB, 128, 0, stream>>>(ts, offs, cntp, perm);
  k_packw<<<384, 256, 0, stream>>>(wih0, whh0, wih1, whh1, wfrag);

  for (int t0 = 0; t0 < LT; t0 += Tc) {
    int Ta = (LT - t0 < Tc) ? (LT - t0) : Tc;
    int first = (t0 == 0);
    int save = (t0 + Ta < LT);
    int last = (t0 + Ta == LT);
    // layer 0 input projection (gathered x, pads -> b_ih)
    k_xgemm<<<dim3(Ta * 16, 6), 256, 0, stream>>>(
        x, (const unsigned short*)nullptr, 0, perm, t0, wfrag, bih0, xgA);
    // layer 0 recurrence -> h1buf
    k_recur<<<128, 1024, 0, stream>>>(
        wfrag + 1 * 196608, bhh0, xgA, Ta, h0s, first, save, h1buf,
        (float*)nullptr, (float*)nullptr, 0, 0);
    // layer 1 input projection (dense h1)
    k_xgemm<<<dim3(Ta * 16, 6), 256, 0, stream>>>(
        (const float*)nullptr, h1buf, 1, (const int*)nullptr, 0,
        wfrag + 2 * 196608, bih1, xgB);
    // layer 1 recurrence -> mean accumulation / output
    k_recur<<<128, 1024, 0, stream>>>(
        wfrag + 3 * 196608, bhh1, xgB, Ta, h1s, first, save,
        (unsigned short*)nullptr, sums, out, last, 1);
  }
}

// Round 2
// 1544.521 us; speedup vs baseline: 1.3369x; 1.3369x over previous
//
#include <hip/hip_runtime.h>

// ---------------------------------------------------------------------------
// GRUAgg: ragged groups -> dense [B,96,D] (timestamp-sorted, zero-padded head)
// -> 2-layer GRU (PyTorch gate order r,z,n) -> mean over 96 steps.
// B=2048, L=96, D=256, 3D=768, E=131072.
// ---------------------------------------------------------------------------

typedef short bh8 __attribute__((ext_vector_type(8)));   // 8 bf16 in 4 VGPRs
typedef float f4  __attribute__((ext_vector_type(4)));   // MFMA accumulator

#define NB 2048
#define LT 96
#define DF 256
#define NG 768

// h LDS frag layout: [kt(8)][lane(64)][j(8)] bf16; element (row,col) of h:
#define LHA(col, row) (((((col) >> 5) * 64 + (((col) >> 3) & 3) * 16 + (row)) * 8) + ((col) & 7))

static __device__ __forceinline__ unsigned short f2b(float f) {
  union { float f; unsigned int u; } v; v.f = f;
  unsigned int r = v.u + 0x7fffu + ((v.u >> 16) & 1u);   // RNE
  return (unsigned short)(r >> 16);
}
static __device__ __forceinline__ float b2f(unsigned short s) {
  union { unsigned int u; float f; } v; v.u = ((unsigned int)s) << 16; return v.f;
}
static __device__ __forceinline__ float sigm(float x) { return 1.0f / (1.0f + __expf(-x)); }
static __device__ __forceinline__ float tanh_(float x) { return 2.0f / (1.0f + __expf(-2.0f * x)) - 1.0f; }

// --------------------------- group offsets/counts ---------------------------
__global__ void k_offsets(const int* __restrict__ idx, int E,
                          int* __restrict__ offs, int* __restrict__ cnt) {
  int b = blockIdx.x * blockDim.x + threadIdx.x;
  if (b >= NB) return;
  int lo = 0, hi = E;
  while (lo < hi) { int m = (lo + hi) >> 1; if (idx[m] < b) lo = m + 1; else hi = m; }
  int lb = lo;
  lo = lb; hi = E;
  while (lo < hi) { int m = (lo + hi) >> 1; if (idx[m] < b + 1) lo = m + 1; else hi = m; }
  offs[b] = lb;
  cnt[b] = lo - lb;
}

// ------------- per-group stable timestamp rank -> slot permutation ----------
__global__ void k_rank(const float* __restrict__ ts, const int* __restrict__ offs,
                       const int* __restrict__ cnt, int* __restrict__ perm) {
  __shared__ float sts[96];
  int b = blockIdx.x, j = threadIdx.x;
  int o = offs[b];
  int c = cnt[b]; if (c > 96) c = 96;
  if (j < 96) perm[b * 96 + j] = -1;
  if (j < c) sts[j] = ts[o + j];
  __syncthreads();
  if (j < c) {
    float tj = sts[j];
    int rank = 0;
    for (int k = 0; k < c; ++k) {
      float tk = sts[k];
      rank += (tk < tj) || (tk == tj && k < j);
    }
    int slot = (tj > 0.0f ? (96 - c) : 0) + rank;
    perm[b * 96 + slot] = o + j;
  }
}

// ------------- pack 4 weight matrices into MFMA B-fragment order ------------
// value(nt,kt,lane,j) = W[n][k], n = nt*16+(lane&15), k = kt*32+(lane>>4)*8+j
// layout: [mat(4)][nt(48)][kt(8)][lane(64)][j(8)] bf16
__global__ void k_packw(const float* __restrict__ w0, const float* __restrict__ w1,
                        const float* __restrict__ w2, const float* __restrict__ w3,
                        unsigned short* __restrict__ wfrag) {
  int t = blockIdx.x * blockDim.x + threadIdx.x;
  if (t >= 4 * 48 * 8 * 64) return;
  int m = t / 24576;
  int r = t % 24576;
  int nt = r / 512;
  int kt = (r / 64) & 7;
  int lane = r & 63;
  int n = nt * 16 + (lane & 15);
  int kb = kt * 32 + (lane >> 4) * 8;
  const float* W = (m == 0) ? w0 : (m == 1) ? w1 : (m == 2) ? w2 : w3;
  unsigned int o[4];
#pragma unroll
  for (int p = 0; p < 4; ++p) {
    unsigned short a = f2b(W[n * 256 + kb + 2 * p]);
    unsigned short b = f2b(W[n * 256 + kb + 2 * p + 1]);
    o[p] = (unsigned int)a | ((unsigned int)b << 16);
  }
  uint4 v; v.x = o[0]; v.y = o[1]; v.z = o[2]; v.w = o[3];
  *(uint4*)&wfrag[(size_t)t * 8] = v;
}

// --------------------------- input-projection GEMM --------------------------
// C[rows][768] = A[rows][256] @ W^T + b_ih, bf16 in/out, fp32 accum.
// 128x128 tile, K split in 2 chunks of 128 so LDS = 66.5 KB -> 2 blocks/CU.
// A staged directly into MFMA A-frag layout [msub(8)][kt4(4)][lane(64)][j(8)].
// grid: (6 ntb fastest for A-row L2 reuse, Ta*16 mtiles), block 256 (4 waves).
__launch_bounds__(256, 2)
__global__ void k_xgemm(const float* __restrict__ Ax, const unsigned short* __restrict__ Ab,
                        int amode, const int* __restrict__ perm, int t0,
                        const unsigned short* __restrict__ wfrag, const float* __restrict__ bias,
                        unsigned short* __restrict__ Cout) {
  __shared__ __align__(16) unsigned short lA[16384];  // 32 KB (also fp32 slab in epilogue)
  __shared__ __align__(16) unsigned short lB[16384];  // 32 KB
  __shared__ float lbias[128];
  __shared__ int lsrc[128];

  const int tid = threadIdx.x;
  const int ntb = blockIdx.x, mt = blockIdx.y;

  if (tid < 32) *(f4*)&lbias[tid * 4] = *(const f4*)&bias[ntb * 128 + tid * 4];
  if (amode == 0 && tid < 128) {
    int row = mt * 128 + tid;
    int tt = row >> 11, g = row & 2047;
    lsrc[tid] = perm[g * 96 + t0 + tt];
  }
  __syncthreads();

  const int w = tid >> 6, l = tid & 63, lm = l & 15, lq = l >> 4;
  const int wm = w >> 1, wn = w & 1;
  const unsigned short* wfN = wfrag + (size_t)ntb * 32768;

  f4 acc[4][4];
#pragma unroll
  for (int i = 0; i < 4; ++i)
#pragma unroll
    for (int j = 0; j < 4; ++j) acc[i][j] = (f4){0.f, 0.f, 0.f, 0.f};

  for (int c = 0; c < 2; ++c) {
    // ---- stage A chunk into frag layout (each thread loads its frag's 16B)
#pragma unroll
    for (int s = tid; s < 2048; s += 256) {
      int lane = s & 63, kt4 = (s >> 6) & 3, msub = s >> 8;
      int rlm = lane & 15, rlq = lane >> 4;
      int k = (c * 4 + kt4) * 32 + rlq * 8;
      uint4 v;
      if (amode == 0) {
        int src = lsrc[msub * 16 + rlm];
        if (src >= 0) {
          const float* p = Ax + (size_t)src * 256 + k;
          f4 f0 = *(const f4*)p, f1 = *(const f4*)(p + 4);
          v.x = (unsigned int)f2b(f0.x) | ((unsigned int)f2b(f0.y) << 16);
          v.y = (unsigned int)f2b(f0.z) | ((unsigned int)f2b(f0.w) << 16);
          v.z = (unsigned int)f2b(f1.x) | ((unsigned int)f2b(f1.y) << 16);
          v.w = (unsigned int)f2b(f1.z) | ((unsigned int)f2b(f1.w) << 16);
        } else { v.x = 0u; v.y = 0u; v.z = 0u; v.w = 0u; }
      } else {
        v = *(const uint4*)&Ab[((size_t)mt * 128 + msub * 16 + rlm) * 256 + k];
      }
      *(uint4*)&lA[(size_t)s * 8] = v;
    }
    // ---- stage B chunk (already frag-packed in wfrag)
#pragma unroll
    for (int s = tid; s < 2048; s += 256) {
      int lane = s & 63, kt4 = (s >> 6) & 3, nt = s >> 8;
      *(uint4*)&lB[(size_t)s * 8] =
          *(const uint4*)&wfN[((nt * 8 + c * 4 + kt4) * 64 + lane) * 8];
    }
    __syncthreads();
#pragma unroll
    for (int kt4 = 0; kt4 < 4; ++kt4) {
      bh8 a[4], b[4];
#pragma unroll
      for (int i = 0; i < 4; ++i) {
        a[i] = *(const bh8*)&lA[(((4 * wm + i) * 4 + kt4) * 64 + l) * 8];
        b[i] = *(const bh8*)&lB[(((4 * wn + i) * 4 + kt4) * 64 + l) * 8];
      }
#pragma unroll
      for (int mi = 0; mi < 4; ++mi)
#pragma unroll
        for (int ni = 0; ni < 4; ++ni)
          acc[mi][ni] = __builtin_amdgcn_mfma_f32_16x16x32_bf16(a[mi], b[ni], acc[mi][ni], 0, 0, 0);
    }
    __syncthreads();
  }

  // ---- epilogue: 4 rounds of 32 rows through an fp32 slab (reuses lA)
  float* slab = (float*)lA;  // [32][132]
  for (int r4 = 0; r4 < 4; ++r4) {
    if (wm == (r4 >> 1)) {
      int mi0 = (2 * r4) & 3;
#pragma unroll
      for (int dm = 0; dm < 2; ++dm)
#pragma unroll
        for (int ni = 0; ni < 4; ++ni) {
          int colc = (4 * wn + ni) * 16 + lm;
          float bv = lbias[colc];
#pragma unroll
          for (int r = 0; r < 4; ++r)
            slab[(dm * 16 + lq * 4 + r) * 132 + colc] = acc[mi0 + dm][ni][r] + bv;
        }
    }
    __syncthreads();
    {
      int row = tid >> 3, cg = tid & 7;
      size_t grow = (size_t)mt * 128 + r4 * 32 + row;
      const float* sp = &slab[row * 132 + cg * 16];
      f4 v0 = *(const f4*)(sp + 0), v1 = *(const f4*)(sp + 4);
      f4 v2 = *(const f4*)(sp + 8), v3 = *(const f4*)(sp + 12);
      uint4 o0, o1;
      o0.x = (unsigned int)f2b(v0.x) | ((unsigned int)f2b(v0.y) << 16);
      o0.y = (unsigned int)f2b(v0.z) | ((unsigned int)f2b(v0.w) << 16);
      o0.z = (unsigned int)f2b(v1.x) | ((unsigned int)f2b(v1.y) << 16);
      o0.w = (unsigned int)f2b(v1.z) | ((unsigned int)f2b(v1.w) << 16);
      o1.x = (unsigned int)f2b(v2.x) | ((unsigned int)f2b(v2.y) << 16);
      o1.y = (unsigned int)f2b(v2.z) | ((unsigned int)f2b(v2.w) << 16);
      o1.z = (unsigned int)f2b(v3.x) | ((unsigned int)f2b(v3.y) << 16);
      o1.w = (unsigned int)f2b(v3.z) | ((unsigned int)f2b(v3.w) << 16);
      unsigned short* cp = &Cout[grow * NG + ntb * 128 + cg * 16];
      *(uint4*)cp = o0;
      *(uint4*)(cp + 8) = o1;
    }
    __syncthreads();
  }
}

// ------------------------------ recurrent core ------------------------------
// 256 blocks x 512 thr (8 waves). Block owns 8 groups (rows 0-7 of the MFMA
// M=16 tile; rows 8-15 stay zero). Wave w owns h-cols {32w+lm, 32w+16+lm}:
//   r gate: ntiles 2w,2w+1   (B-frags in VGPRs, 64 regs)
//   z gate: ntiles 16+2w,..  (B-frags in VGPRs, 64 regs)
//   n gate: ntiles 32+2w,..  (B-frags in LDS, 128 KB)
// h: fp32 master in registers; bf16 copy double-buffered in LDS frag layout
// (conflict-free ds_read_b128, 1 barrier/step).
__launch_bounds__(512, 2)
__global__ void k_recur(const unsigned short* __restrict__ wf,  // this layer's W_hh frags
                        const float* __restrict__ bhh,
                        const unsigned short* __restrict__ xg,  // [tt*2048+g][768] bf16
                        int Ta, float* __restrict__ hstate, int first, int save,
                        unsigned short* __restrict__ h1out,     // layer0 out or null
                        float* __restrict__ sumstate, float* __restrict__ outp,
                        int last, int layer) {
  __shared__ __align__(16) unsigned short lBn[65536];   // 128 KB n-gate frags
  __shared__ __align__(16) unsigned short lh[2][4096];  // 16 KB double-buffered h frags

  const int tid = threadIdx.x;
  const int w = tid >> 6, l = tid & 63, lm = l & 15, lq = l >> 4;
  const int g0 = blockIdx.x * 8;
  const int col0 = w * 32 + lm, col1 = col0 + 16;

  // r,z gate B-fragments resident in VGPRs (unrolled/const-indexed).
  bh8 br0[8], br1[8], bz0[8], bz1[8];
#pragma unroll
  for (int kt = 0; kt < 8; ++kt) {
    br0[kt] = *(const bh8*)&wf[(((2 * w + 0) * 8 + kt) * 64 + l) * 8];
    br1[kt] = *(const bh8*)&wf[(((2 * w + 1) * 8 + kt) * 64 + l) * 8];
    bz0[kt] = *(const bh8*)&wf[(((16 + 2 * w) * 8 + kt) * 64 + l) * 8];
    bz1[kt] = *(const bh8*)&wf[(((17 + 2 * w) * 8 + kt) * 64 + l) * 8];
  }
  const float bhr0 = bhh[col0], bhr1 = bhh[col1];
  const float bhz0 = bhh[256 + col0], bhz1 = bhh[256 + col1];
  const float bhn0 = bhh[512 + col0], bhn1 = bhh[512 + col1];

  {  // n-gate frags (ntiles 32-47) -> LDS
    const uint4* sp = (const uint4*)(wf + 131072);
    uint4* d = (uint4*)lBn;
    for (int i = tid; i < 8192; i += 512) d[i] = sp[i];
  }
  {  // zero both h buffers (rows 8-15 must be 0 forever)
    uint4 z; z.x = 0u; z.y = 0u; z.z = 0u; z.w = 0u;
    uint4* d = (uint4*)lh;
    for (int i = tid; i < 1024; i += 512) d[i] = z;
  }
  __syncthreads();

  float hp0[4], hp1[4], sm0[4], sm1[4];
  const int act = (lq < 2);
  if (act) {
#pragma unroll
    for (int reg = 0; reg < 4; ++reg) {
      int row = lq * 4 + reg;
      float a0 = first ? 0.f : hstate[(size_t)(g0 + row) * DF + col0];
      float a1 = first ? 0.f : hstate[(size_t)(g0 + row) * DF + col1];
      hp0[reg] = a0; hp1[reg] = a1;
      lh[0][LHA(col0, row)] = f2b(a0);
      lh[0][LHA(col1, row)] = f2b(a1);
      if (layer == 1 && !first) {
        sm0[reg] = sumstate[(size_t)(g0 + row) * DF + col0];
        sm1[reg] = sumstate[(size_t)(g0 + row) * DF + col1];
      } else { sm0[reg] = 0.f; sm1[reg] = 0.f; }
    }
  }
  __syncthreads();

  int cur = 0;
  for (int tt = 0; tt < Ta; ++tt) {
    // xg preactivations (issued before MFMA phase; consumed after -> latency hidden)
    float xr0[4], xr1[4], xz0[4], xz1[4], xn0[4], xn1[4];
    if (act) {
      size_t base = ((size_t)tt * NB + g0 + lq * 4) * NG;
#pragma unroll
      for (int reg = 0; reg < 4; ++reg) {
        size_t rb = base + (size_t)reg * NG;
        xr0[reg] = b2f(xg[rb + col0]);        xr1[reg] = b2f(xg[rb + col1]);
        xz0[reg] = b2f(xg[rb + 256 + col0]);  xz1[reg] = b2f(xg[rb + 256 + col1]);
        xn0[reg] = b2f(xg[rb + 512 + col0]);  xn1[reg] = b2f(xg[rb + 512 + col1]);
      }
    }
    f4 ar0 = (f4){0.f, 0.f, 0.f, 0.f}, ar1 = (f4){0.f, 0.f, 0.f, 0.f};
    f4 az0 = (f4){0.f, 0.f, 0.f, 0.f}, az1 = (f4){0.f, 0.f, 0.f, 0.f};
    f4 an0 = (f4){0.f, 0.f, 0.f, 0.f}, an1 = (f4){0.f, 0.f, 0.f, 0.f};
    const unsigned short* hc = lh[cur];
#pragma unroll
    for (int kt = 0; kt < 8; ++kt) {
      bh8 a = *(const bh8*)&hc[(kt * 64 + l) * 8];
      ar0 = __builtin_amdgcn_mfma_f32_16x16x32_bf16(a, br0[kt], ar0, 0, 0, 0);
      ar1 = __builtin_amdgcn_mfma_f32_16x16x32_bf16(a, br1[kt], ar1, 0, 0, 0);
      az0 = __builtin_amdgcn_mfma_f32_16x16x32_bf16(a, bz0[kt], az0, 0, 0, 0);
      az1 = __builtin_amdgcn_mfma_f32_16x16x32_bf16(a, bz1[kt], az1, 0, 0, 0);
      bh8 n0 = *(const bh8*)&lBn[(((2 * w + 0) * 8 + kt) * 64 + l) * 8];
      bh8 n1 = *(const bh8*)&lBn[(((2 * w + 1) * 8 + kt) * 64 + l) * 8];
      an0 = __builtin_amdgcn_mfma_f32_16x16x32_bf16(a, n0, an0, 0, 0, 0);
      an1 = __builtin_amdgcn_mfma_f32_16x16x32_bf16(a, n1, an1, 0, 0, 0);
    }
    unsigned short* hn = lh[cur ^ 1];
    if (act) {
#pragma unroll
      for (int reg = 0; reg < 4; ++reg) {
        int row = lq * 4 + reg;
        float r0 = sigm(xr0[reg] + ar0[reg] + bhr0);
        float z0 = sigm(xz0[reg] + az0[reg] + bhz0);
        float n0v = tanh_(xn0[reg] + r0 * (an0[reg] + bhn0));
        float h0 = (1.f - z0) * n0v + z0 * hp0[reg]; hp0[reg] = h0;
        float r1 = sigm(xr1[reg] + ar1[reg] + bhr1);
        float z1 = sigm(xz1[reg] + az1[reg] + bhz1);
        float n1v = tanh_(xn1[reg] + r1 * (an1[reg] + bhn1));
        float h1 = (1.f - z1) * n1v + z1 * hp1[reg]; hp1[reg] = h1;
        hn[LHA(col0, row)] = f2b(h0);
        hn[LHA(col1, row)] = f2b(h1);
        if (layer == 0) {
          size_t ob = ((size_t)tt * NB + g0 + row) * DF;
          h1out[ob + col0] = f2b(h0);
          h1out[ob + col1] = f2b(h1);
        } else {
          sm0[reg] += h0; sm1[reg] += h1;
        }
      }
    }
    __syncthreads();
    cur ^= 1;
  }

  if (act) {
    if (save) {
#pragma unroll
      for (int reg = 0; reg < 4; ++reg) {
        int row = lq * 4 + reg;
        hstate[(size_t)(g0 + row) * DF + col0] = hp0[reg];
        hstate[(size_t)(g0 + row) * DF + col1] = hp1[reg];
      }
    }
    if (layer == 1) {
      if (last) {
#pragma unroll
        for (int reg = 0; reg < 4; ++reg) {
          int row = lq * 4 + reg;
          outp[(size_t)(g0 + row) * DF + col0] = sm0[reg] * (1.0f / 96.0f);
          outp[(size_t)(g0 + row) * DF + col1] = sm1[reg] * (1.0f / 96.0f);
        }
      } else {
#pragma unroll
        for (int reg = 0; reg < 4; ++reg) {
          int row = lq * 4 + reg;
          sumstate[(size_t)(g0 + row) * DF + col0] = sm0[reg];
          sumstate[(size_t)(g0 + row) * DF + col1] = sm1[reg];
        }
      }
    }
  }
}

// ------------------------------- host launcher ------------------------------
extern "C" void kernel_launch(void* const* d_in, const int* in_sizes, int n_in,
                              void* d_out, int out_size, void* d_ws, size_t ws_size,
                              hipStream_t stream) {
  (void)n_in; (void)out_size;
  const float* x    = (const float*)d_in[0];
  const float* ts   = (const float*)d_in[1];
  const float* wih0 = (const float*)d_in[2];
  const float* whh0 = (const float*)d_in[3];
  const float* bih0 = (const float*)d_in[4];
  const float* bhh0 = (const float*)d_in[5];
  const float* wih1 = (const float*)d_in[6];
  const float* whh1 = (const float*)d_in[7];
  const float* bih1 = (const float*)d_in[8];
  const float* bhh1 = (const float*)d_in[9];
  const int*   idx  = (const int*)d_in[10];
  float* out = (float*)d_out;
  const int E = in_sizes[0] / DF;

  char* wsb = (char*)d_ws;
  size_t off = 0;
  auto carve = [&](size_t bytes) -> char* {
    off = (off + 255) & ~(size_t)255;
    char* p = wsb + off;
    off += bytes;
    return p;
  };
  int* offs = (int*)carve((size_t)NB * 4);
  int* cntp = (int*)carve((size_t)NB * 4);
  int* perm = (int*)carve((size_t)NB * LT * 4);
  unsigned short* wfrag = (unsigned short*)carve((size_t)4 * 196608 * 2);
  float* h0s  = (float*)carve((size_t)NB * DF * 4);
  float* h1s  = (float*)carve((size_t)NB * DF * 4);
  float* sums = (float*)carve((size_t)NB * DF * 4);
  size_t fixedBytes = off;

  const size_t perT = (size_t)NB * DF * 2 + 2 * (size_t)NB * NG * 2;  // 7,340,032 B
  int Tc = 1;
  if (ws_size > fixedBytes + 4096) {
    size_t t = (ws_size - fixedBytes - 4096) / perT;
    Tc = (int)(t > 96 ? 96 : (t < 1 ? 1 : t));
  }
  unsigned short* h1buf = (unsigned short*)carve((size_t)Tc * NB * DF * 2);
  unsigned short* xgA   = (unsigned short*)carve((size_t)Tc * NB * NG * 2);
  unsigned short* xgB   = (unsigned short*)carve((size_t)Tc * NB * NG * 2);

  k_offsets<<<8, 256, 0, stream>>>(idx, E, offs, cntp);
  k_rank<<<NB, 128, 0, stream>>>(ts, offs, cntp, perm);
  k_packw<<<384, 256, 0, stream>>>(wih0, whh0, wih1, whh1, wfrag);

  for (int t0 = 0; t0 < LT; t0 += Tc) {
    int Ta = (LT - t0 < Tc) ? (LT - t0) : Tc;
    int first = (t0 == 0);
    int save = (t0 + Ta < LT);
    int last = (t0 + Ta == LT);
    // layer 0 input projection (gathered x, pads -> b_ih)
    k_xgemm<<<dim3(6, Ta * 16), 256, 0, stream>>>(
        x, (const unsigned short*)nullptr, 0, perm, t0, wfrag, bih0, xgA);
    // layer 0 recurrence -> h1buf
    k_recur<<<256, 512, 0, stream>>>(
        wfrag + 1 * 196608, bhh0, xgA, Ta, h0s, first, save, h1buf,
        (float*)nullptr, (float*)nullptr, 0, 0);
    // layer 1 input projection (dense h1)
    k_xgemm<<<dim3(6, Ta * 16), 256, 0, stream>>>(
        (const float*)nullptr, h1buf, 1, (const int*)nullptr, 0,
        wfrag + 2 * 196608, bih1, xgB);
    // layer 1 recurrence -> mean accumulation / output
    k_recur<<<256, 512, 0, stream>>>(
        wfrag + 3 * 196608, bhh1, xgB, Ta, h1s, first, save,
        (unsigned short*)nullptr, sums, out, last, 1);
  }
}

// Round 3
// 1314.507 us; speedup vs baseline: 1.5709x; 1.1750x over previous
//
#include <hip/hip_runtime.h>

// ---------------------------------------------------------------------------
// GRUAgg: ragged groups -> dense [B,96,D] (timestamp-sorted, zero-padded head)
// -> 2-layer GRU (PyTorch gate order r,z,n) -> mean over 96 steps.
// B=2048, L=96, D=256, 3D=768, E=131072.
// ---------------------------------------------------------------------------

typedef short bh8 __attribute__((ext_vector_type(8)));   // 8 bf16 in 4 VGPRs
typedef float f4  __attribute__((ext_vector_type(4)));   // MFMA accumulator

#define NB 2048
#define LT 96
#define DF 256
#define NG 768
#define XJ 192   // xgemm persistent-block count per ntb

// h LDS frag layout: [kt(8)][lane(64)][j(8)] bf16; element (row,col) of h:
#define LHA(col, row) (((((col) >> 5) * 64 + (((col) >> 3) & 3) * 16 + (row)) * 8) + ((col) & 7))

static __device__ __forceinline__ unsigned short f2b(float f) {
  union { float f; unsigned int u; } v; v.f = f;
  unsigned int r = v.u + 0x7fffu + ((v.u >> 16) & 1u);   // RNE
  return (unsigned short)(r >> 16);
}
static __device__ __forceinline__ float b2f(unsigned short s) {
  union { unsigned int u; float f; } v; v.u = ((unsigned int)s) << 16; return v.f;
}
static __device__ __forceinline__ unsigned int pk2(float a, float b) {
  return (unsigned int)f2b(a) | ((unsigned int)f2b(b) << 16);
}
static __device__ __forceinline__ float sigm(float x) { return 1.0f / (1.0f + __expf(-x)); }
static __device__ __forceinline__ float tanh_(float x) { return 2.0f / (1.0f + __expf(-2.0f * x)) - 1.0f; }

// --------------------------- group offsets/counts ---------------------------
__global__ void k_offsets(const int* __restrict__ idx, int E,
                          int* __restrict__ offs, int* __restrict__ cnt) {
  int b = blockIdx.x * blockDim.x + threadIdx.x;
  if (b >= NB) return;
  int lo = 0, hi = E;
  while (lo < hi) { int m = (lo + hi) >> 1; if (idx[m] < b) lo = m + 1; else hi = m; }
  int lb = lo;
  lo = lb; hi = E;
  while (lo < hi) { int m = (lo + hi) >> 1; if (idx[m] < b + 1) lo = m + 1; else hi = m; }
  offs[b] = lb;
  cnt[b] = lo - lb;
}

// ------------- per-group stable timestamp rank -> slot permutation ----------
__global__ void k_rank(const float* __restrict__ ts, const int* __restrict__ offs,
                       const int* __restrict__ cnt, int* __restrict__ perm) {
  __shared__ float sts[96];
  int b = blockIdx.x, j = threadIdx.x;
  int o = offs[b];
  int c = cnt[b]; if (c > 96) c = 96;
  if (j < 96) perm[b * 96 + j] = -1;
  if (j < c) sts[j] = ts[o + j];
  __syncthreads();
  if (j < c) {
    float tj = sts[j];
    int rank = 0;
    for (int k = 0; k < c; ++k) {
      float tk = sts[k];
      rank += (tk < tj) || (tk == tj && k < j);
    }
    int slot = (tj > 0.0f ? (96 - c) : 0) + rank;
    perm[b * 96 + slot] = o + j;
  }
}

// ------------- pack 4 weight matrices into MFMA B-fragment order ------------
// value(nt,kt,lane,j) = W[n][k], n = nt*16+(lane&15), k = kt*32+(lane>>4)*8+j
// layout: [mat(4)][nt(48)][kt(8)][lane(64)][j(8)] bf16
__global__ void k_packw(const float* __restrict__ w0, const float* __restrict__ w1,
                        const float* __restrict__ w2, const float* __restrict__ w3,
                        unsigned short* __restrict__ wfrag) {
  int t = blockIdx.x * blockDim.x + threadIdx.x;
  if (t >= 4 * 48 * 8 * 64) return;
  int m = t / 24576;
  int r = t % 24576;
  int nt = r / 512;
  int kt = (r / 64) & 7;
  int lane = r & 63;
  int n = nt * 16 + (lane & 15);
  int kb = kt * 32 + (lane >> 4) * 8;
  const float* W = (m == 0) ? w0 : (m == 1) ? w1 : (m == 2) ? w2 : w3;
  unsigned int o[4];
#pragma unroll
  for (int p = 0; p < 4; ++p)
    o[p] = pk2(W[n * 256 + kb + 2 * p], W[n * 256 + kb + 2 * p + 1]);
  uint4 v; v.x = o[0]; v.y = o[1]; v.z = o[2]; v.w = o[3];
  *(uint4*)&wfrag[(size_t)t * 8] = v;
}

// --------------------------- input-projection GEMM --------------------------
// C[rows][768] = A[rows][256] @ W^T + bias, bf16 out, fp32 accum.
// Persistent: grid 6*XJ blocks; block (ntb, jb) holds its 2-ntile-per-wave B
// fragments in VGPRs and loops over 64-row slabs jb, jb+XJ, ... staging A
// through double-buffered LDS with register prefetch across slabs.
template <int AMODE>
__launch_bounds__(256, 2)
__global__ void k_xgemm(const float* __restrict__ Ax, const unsigned short* __restrict__ Ab,
                        const int* __restrict__ perm, int t0, int slabsTotal,
                        const unsigned short* __restrict__ wfrag, const float* __restrict__ bias,
                        unsigned short* __restrict__ Cout) {
  // each buffer: A-frag bf16 (32768 B) or fp32 slab 64 x 140 (35840 B)
  __shared__ float lsm[2][8960];

  const int tid = threadIdx.x;
  const int ntb = blockIdx.x % 6;
  const int jb  = blockIdx.x / 6;
  if (jb >= slabsTotal) return;
  const int w = tid >> 6, l = tid & 63, lm = l & 15, lq = l >> 4;

  // B fragments resident in VGPRs: wave w owns ntiles 2w, 2w+1 of this ntb.
  const unsigned short* wfN = wfrag + (size_t)ntb * 32768;
  bh8 bf[2][8];
#pragma unroll
  for (int i = 0; i < 2; ++i)
#pragma unroll
    for (int kt = 0; kt < 8; ++kt)
      bf[i][kt] = *(const bh8*)&wfN[(((2 * w + i) * 8 + kt) * 64 + l) * 8];
  const float bias0 = bias[ntb * 128 + (2 * w + 0) * 16 + lm];
  const float bias1 = bias[ntb * 128 + (2 * w + 1) * 16 + lm];

  // staging geometry: thread covers row trow, float cols 64*tp .. 64*tp+63
  const int trow = tid >> 2, tp = tid & 3;
  const int msub = trow >> 4, rlm = trow & 15;

  f4 pf[16];      // AMODE 0 prefetch (fp32)
  uint4 pb[8];    // AMODE 1 prefetch (bf16)

  auto issue_loads = [&](int s) {
    int row = s * 64 + trow;
    if (AMODE == 0) {
      int tt = row >> 11, g = row & 2047;
      int src = perm[g * 96 + t0 + tt];
      if (src >= 0) {
        const float* p = Ax + (size_t)src * 256 + tp * 64;
#pragma unroll
        for (int i = 0; i < 16; ++i) pf[i] = *(const f4*)(p + 4 * i);
      } else {
#pragma unroll
        for (int i = 0; i < 16; ++i) pf[i] = (f4){0.f, 0.f, 0.f, 0.f};
      }
    } else {
      const unsigned short* p = Ab + (size_t)row * 256 + tp * 64;
#pragma unroll
      for (int i = 0; i < 8; ++i) pb[i] = *(const uint4*)(p + 8 * i);
    }
  };
  auto write_afrag = [&](int buf) {
    unsigned short* aN = (unsigned short*)lsm[buf];
#pragma unroll
    for (int kk = 0; kk < 2; ++kk)
#pragma unroll
      for (int rlq = 0; rlq < 4; ++rlq) {
        int kt = 2 * tp + kk;
        unsigned short* d = &aN[(((msub * 8 + kt) * 64) + rlq * 16 + rlm) * 8];
        if (AMODE == 0) {
          f4 f0 = pf[8 * kk + 2 * rlq], f1 = pf[8 * kk + 2 * rlq + 1];
          uint4 v;
          v.x = pk2(f0.x, f0.y); v.y = pk2(f0.z, f0.w);
          v.z = pk2(f1.x, f1.y); v.w = pk2(f1.z, f1.w);
          *(uint4*)d = v;
        } else {
          *(uint4*)d = pb[4 * kk + rlq];
        }
      }
  };

  // prologue: stage first slab
  issue_loads(jb);
  write_afrag(0);
  __syncthreads();

  int cur = 0;
  for (int s = jb; s < slabsTotal; s += XJ) {
    const int snext = s + XJ;
    const bool hasNext = snext < slabsTotal;
    if (hasNext) issue_loads(snext);

    // MFMA from buf[cur]
    const unsigned short* aC = (const unsigned short*)lsm[cur];
    f4 acc[4][2];
#pragma unroll
    for (int m = 0; m < 4; ++m)
#pragma unroll
      for (int n = 0; n < 2; ++n) acc[m][n] = (f4){0.f, 0.f, 0.f, 0.f};
#pragma unroll
    for (int kt = 0; kt < 8; ++kt) {
      bh8 a[4];
#pragma unroll
      for (int m = 0; m < 4; ++m) a[m] = *(const bh8*)&aC[((m * 8 + kt) * 64 + l) * 8];
#pragma unroll
      for (int m = 0; m < 4; ++m) {
        acc[m][0] = __builtin_amdgcn_mfma_f32_16x16x32_bf16(a[m], bf[0][kt], acc[m][0], 0, 0, 0);
        acc[m][1] = __builtin_amdgcn_mfma_f32_16x16x32_bf16(a[m], bf[1][kt], acc[m][1], 0, 0, 0);
      }
    }

    // epilogue: acc + bias -> fp32 slab in buf[cur^1] (swizzled: phys = col + 4*(col>>5))
    float* sl = lsm[cur ^ 1];
#pragma unroll
    for (int m = 0; m < 4; ++m)
#pragma unroll
      for (int n = 0; n < 2; ++n) {
        int phys = 36 * w + 16 * n + lm;   // col = (2w+n)*16+lm, col>>5 == w
        float bv = n ? bias1 : bias0;
#pragma unroll
        for (int r = 0; r < 4; ++r)
          sl[(m * 16 + lq * 4 + r) * 140 + phys] = acc[m][n][r] + bv;
      }
    __syncthreads();

    // coalesced C store from slab: thread -> (trow, cols 32*tp..+31)
    {
      const float* sp = &sl[trow * 140 + 36 * tp];
      unsigned short* cp = &Cout[((size_t)s * 64 + trow) * NG + ntb * 128 + tp * 32];
#pragma unroll
      for (int i = 0; i < 4; ++i) {
        f4 v0 = *(const f4*)(sp + 8 * i), v1 = *(const f4*)(sp + 8 * i + 4);
        uint4 o;
        o.x = pk2(v0.x, v0.y); o.y = pk2(v0.z, v0.w);
        o.z = pk2(v1.x, v1.y); o.w = pk2(v1.z, v1.w);
        *(uint4*)(cp + 8 * i) = o;
      }
    }
    __syncthreads();

    if (hasNext) {
      write_afrag(cur ^ 1);
      __syncthreads();
    }
    cur ^= 1;
  }
}

// ------------------------------ recurrent core ------------------------------
// 256 blocks x 512 thr (8 waves), 1 block/CU. Block owns 8 groups (rows 0-7
// of the MFMA M=16 tile; rows 8-15 stay zero). Wave w owns h-cols
// {32w+lm, 32w+16+lm}: r ntiles 2w,2w+1 + z ntiles 16+2w,17+2w + n ntile
// 32+2w in VGPRs (160 regs); n ntile 33+2w streamed from LDS (64 KB).
// xg: contiguous 12 KB/step, reg-prefetched one step ahead into a
// double-buffered LDS slab; gate phase reads ds_read_u16 (no global scalars).
template <int LAYER>
__launch_bounds__(512, 2)
__global__ void k_recur(const unsigned short* __restrict__ wf, const float* __restrict__ bhh,
                        const unsigned short* __restrict__ xg, int Ta,
                        float* __restrict__ hstate, int first, int save,
                        unsigned short* __restrict__ h1out,
                        float* __restrict__ sumstate, float* __restrict__ outp, int last) {
  __shared__ __align__(16) unsigned short lBn[32768];     // 64 KB: n ntile 33+2w per wave
  __shared__ __align__(16) unsigned short lh[2][4096];    // 16 KB: h frags, double-buffered
  __shared__ __align__(16) unsigned short lxg[2][6144];   // 24 KB: xg slab, double-buffered

  const int tid = threadIdx.x;
  const int w = tid >> 6, l = tid & 63, lm = l & 15, lq = l >> 4;
  const int g0 = blockIdx.x * 8;
  const int col0 = w * 32 + lm, col1 = col0 + 16;
  const int act = (lq < 2);

  // VGPR-resident B fragments: r (2), z (2), n (1)
  bh8 br0[8], br1[8], bz0[8], bz1[8], bn0[8];
#pragma unroll
  for (int kt = 0; kt < 8; ++kt) {
    br0[kt] = *(const bh8*)&wf[(((2 * w + 0) * 8 + kt) * 64 + l) * 8];
    br1[kt] = *(const bh8*)&wf[(((2 * w + 1) * 8 + kt) * 64 + l) * 8];
    bz0[kt] = *(const bh8*)&wf[(((16 + 2 * w) * 8 + kt) * 64 + l) * 8];
    bz1[kt] = *(const bh8*)&wf[(((17 + 2 * w) * 8 + kt) * 64 + l) * 8];
    bn0[kt] = *(const bh8*)&wf[(((32 + 2 * w) * 8 + kt) * 64 + l) * 8];
  }
  const float bhr0 = bhh[col0], bhr1 = bhh[col1];
  const float bhz0 = bhh[256 + col0], bhz1 = bhh[256 + col1];
  const float bhn0 = bhh[512 + col0], bhn1 = bhh[512 + col1];

  {  // n ntile 33+2w' -> LDS
    for (int i = tid; i < 4096; i += 512) {
      int wp = i >> 9, kt = (i >> 6) & 7, lane = i & 63;
      ((uint4*)lBn)[i] = *(const uint4*)&wf[(((33 + 2 * wp) * 8 + kt) * 64 + lane) * 8];
    }
  }
  {  // zero both h buffers (rows 8-15 stay 0 forever)
    uint4 z; z.x = 0u; z.y = 0u; z.z = 0u; z.w = 0u;
    for (int i = tid; i < 1024; i += 512) ((uint4*)lh)[i] = z;
  }
  __syncthreads();

  float hp0[4], hp1[4], sm0[4], sm1[4];
  if (act) {
#pragma unroll
    for (int reg = 0; reg < 4; ++reg) {
      int row = lq * 4 + reg;
      float a0 = first ? 0.f : hstate[(size_t)(g0 + row) * DF + col0];
      float a1 = first ? 0.f : hstate[(size_t)(g0 + row) * DF + col1];
      hp0[reg] = a0; hp1[reg] = a1;
      lh[0][LHA(col0, row)] = f2b(a0);
      lh[0][LHA(col1, row)] = f2b(a1);
      if (LAYER == 1) {
        if (!first) {
          sm0[reg] = sumstate[(size_t)(g0 + row) * DF + col0];
          sm1[reg] = sumstate[(size_t)(g0 + row) * DF + col1];
        } else { sm0[reg] = 0.f; sm1[reg] = 0.f; }
      }
    }
  }
  {  // preload xg(0) into lxg[0]: contiguous 12288 B
    const unsigned short* gp = xg + (size_t)g0 * NG;
    uint4 q0 = *(const uint4*)(gp + tid * 8);
    *(uint4*)&lxg[0][tid * 8] = q0;
    if (tid < 256) {
      uint4 q1 = *(const uint4*)(gp + 4096 + tid * 8);
      *(uint4*)&lxg[0][4096 + tid * 8] = q1;
    }
  }
  __syncthreads();

  int cur = 0;
  for (int tt = 0; tt < Ta; ++tt) {
    const int nxt = cur ^ 1;
    // A) prefetch xg(tt+1) into regs (lands during this step's compute)
    uint4 p0, p1;
    const bool hasN = (tt + 1 < Ta);
    if (hasN) {
      const unsigned short* gp = xg + ((size_t)(tt + 1) * NB + g0) * NG;
      p0 = *(const uint4*)(gp + tid * 8);
      if (tid < 256) p1 = *(const uint4*)(gp + 4096 + tid * 8);
    }
    // B) cooperative h1out store of h(tt) (layer 0), overlaps MFMA
    if (LAYER == 0 && tt > 0 && tid < 256) {
      int row = tid >> 5, c0 = (tid & 31) * 8;
      uint4 hv = *(const uint4*)&lh[cur][(((c0 >> 5) * 64 + ((c0 >> 3) & 3) * 16 + row) * 8)];
      *(uint4*)&h1out[((size_t)(tt - 1) * NB + g0 + row) * DF + c0] = hv;
    }
    // C) MFMA: gates = h @ W_hh^T
    f4 ar0 = (f4){0.f,0.f,0.f,0.f}, ar1 = (f4){0.f,0.f,0.f,0.f};
    f4 az0 = (f4){0.f,0.f,0.f,0.f}, az1 = (f4){0.f,0.f,0.f,0.f};
    f4 an0 = (f4){0.f,0.f,0.f,0.f}, an1 = (f4){0.f,0.f,0.f,0.f};
    const unsigned short* hc = lh[cur];
#pragma unroll
    for (int kt = 0; kt < 8; ++kt) {
      bh8 a = *(const bh8*)&hc[(kt * 64 + l) * 8];
      ar0 = __builtin_amdgcn_mfma_f32_16x16x32_bf16(a, br0[kt], ar0, 0, 0, 0);
      ar1 = __builtin_amdgcn_mfma_f32_16x16x32_bf16(a, br1[kt], ar1, 0, 0, 0);
      az0 = __builtin_amdgcn_mfma_f32_16x16x32_bf16(a, bz0[kt], az0, 0, 0, 0);
      az1 = __builtin_amdgcn_mfma_f32_16x16x32_bf16(a, bz1[kt], az1, 0, 0, 0);
      an0 = __builtin_amdgcn_mfma_f32_16x16x32_bf16(a, bn0[kt], an0, 0, 0, 0);
      bh8 n1 = *(const bh8*)&lBn[((w * 8 + kt) * 64 + l) * 8];
      an1 = __builtin_amdgcn_mfma_f32_16x16x32_bf16(a, n1, an1, 0, 0, 0);
    }
    // D) gate phase: xg from LDS, write h(tt+1) -> lh[nxt]
    if (act) {
      const unsigned short* xc = lxg[cur];
#pragma unroll
      for (int reg = 0; reg < 4; ++reg) {
        int row = lq * 4 + reg;
        int base = row * NG;
        float xr0 = b2f(xc[base + col0]),       xr1 = b2f(xc[base + col1]);
        float xz0 = b2f(xc[base + 256 + col0]), xz1 = b2f(xc[base + 256 + col1]);
        float xn0 = b2f(xc[base + 512 + col0]), xn1 = b2f(xc[base + 512 + col1]);
        float r0 = sigm(xr0 + ar0[reg] + bhr0);
        float z0 = sigm(xz0 + az0[reg] + bhz0);
        float n0 = tanh_(xn0 + r0 * (an0[reg] + bhn0));
        float h0 = (1.f - z0) * n0 + z0 * hp0[reg]; hp0[reg] = h0;
        float r1 = sigm(xr1 + ar1[reg] + bhr1);
        float z1 = sigm(xz1 + az1[reg] + bhz1);
        float n1 = tanh_(xn1 + r1 * (an1[reg] + bhn1));
        float h1 = (1.f - z1) * n1 + z1 * hp1[reg]; hp1[reg] = h1;
        lh[nxt][LHA(col0, row)] = f2b(h0);
        lh[nxt][LHA(col1, row)] = f2b(h1);
        if (LAYER == 1) { sm0[reg] += h0; sm1[reg] += h1; }
      }
    }
    // E) commit xg prefetch to lxg[nxt]
    if (hasN) {
      *(uint4*)&lxg[nxt][tid * 8] = p0;
      if (tid < 256) *(uint4*)&lxg[nxt][4096 + tid * 8] = p1;
    }
    __syncthreads();
    cur = nxt;
  }

  // final h1out block (h(Ta))
  if (LAYER == 0 && tid < 256) {
    int row = tid >> 5, c0 = (tid & 31) * 8;
    uint4 hv = *(const uint4*)&lh[cur][(((c0 >> 5) * 64 + ((c0 >> 3) & 3) * 16 + row) * 8)];
    *(uint4*)&h1out[((size_t)(Ta - 1) * NB + g0 + row) * DF + c0] = hv;
  }
  if (act) {
    if (save) {
#pragma unroll
      for (int reg = 0; reg < 4; ++reg) {
        int row = lq * 4 + reg;
        hstate[(size_t)(g0 + row) * DF + col0] = hp0[reg];
        hstate[(size_t)(g0 + row) * DF + col1] = hp1[reg];
      }
    }
    if (LAYER == 1) {
      if (last) {
#pragma unroll
        for (int reg = 0; reg < 4; ++reg) {
          int row = lq * 4 + reg;
          outp[(size_t)(g0 + row) * DF + col0] = sm0[reg] * (1.0f / 96.0f);
          outp[(size_t)(g0 + row) * DF + col1] = sm1[reg] * (1.0f / 96.0f);
        }
      } else {
#pragma unroll
        for (int reg = 0; reg < 4; ++reg) {
          int row = lq * 4 + reg;
          sumstate[(size_t)(g0 + row) * DF + col0] = sm0[reg];
          sumstate[(size_t)(g0 + row) * DF + col1] = sm1[reg];
        }
      }
    }
  }
}

// ------------------------------- host launcher ------------------------------
extern "C" void kernel_launch(void* const* d_in, const int* in_sizes, int n_in,
                              void* d_out, int out_size, void* d_ws, size_t ws_size,
                              hipStream_t stream) {
  (void)n_in; (void)out_size;
  const float* x    = (const float*)d_in[0];
  const float* ts   = (const float*)d_in[1];
  const float* wih0 = (const float*)d_in[2];
  const float* whh0 = (const float*)d_in[3];
  const float* bih0 = (const float*)d_in[4];
  const float* bhh0 = (const float*)d_in[5];
  const float* wih1 = (const float*)d_in[6];
  const float* whh1 = (const float*)d_in[7];
  const float* bih1 = (const float*)d_in[8];
  const float* bhh1 = (const float*)d_in[9];
  const int*   idx  = (const int*)d_in[10];
  float* out = (float*)d_out;
  const int E = in_sizes[0] / DF;

  char* wsb = (char*)d_ws;
  size_t off = 0;
  auto carve = [&](size_t bytes) -> char* {
    off = (off + 255) & ~(size_t)255;
    char* p = wsb + off;
    off += bytes;
    return p;
  };
  int* offs = (int*)carve((size_t)NB * 4);
  int* cntp = (int*)carve((size_t)NB * 4);
  int* perm = (int*)carve((size_t)NB * LT * 4);
  unsigned short* wfrag = (unsigned short*)carve((size_t)4 * 196608 * 2);
  float* h0s  = (float*)carve((size_t)NB * DF * 4);
  float* h1s  = (float*)carve((size_t)NB * DF * 4);
  float* sums = (float*)carve((size_t)NB * DF * 4);
  size_t fixedBytes = off;

  const size_t perT = (size_t)NB * DF * 2 + 2 * (size_t)NB * NG * 2;  // 7,340,032 B
  int Tc = 1;
  if (ws_size > fixedBytes + 4096) {
    size_t t = (ws_size - fixedBytes - 4096) / perT;
    Tc = (int)(t > 96 ? 96 : (t < 1 ? 1 : t));
  }
  unsigned short* h1buf = (unsigned short*)carve((size_t)Tc * NB * DF * 2);
  unsigned short* xgA   = (unsigned short*)carve((size_t)Tc * NB * NG * 2);
  unsigned short* xgB   = (unsigned short*)carve((size_t)Tc * NB * NG * 2);

  k_offsets<<<8, 256, 0, stream>>>(idx, E, offs, cntp);
  k_rank<<<NB, 128, 0, stream>>>(ts, offs, cntp, perm);
  k_packw<<<384, 256, 0, stream>>>(wih0, whh0, wih1, whh1, wfrag);

  for (int t0 = 0; t0 < LT; t0 += Tc) {
    int Ta = (LT - t0 < Tc) ? (LT - t0) : Tc;
    int first = (t0 == 0);
    int save = (t0 + Ta < LT);
    int last = (t0 + Ta == LT);
    int slabs = Ta * 32;
    // layer 0 input projection (gathered x, pads -> b_ih)
    k_xgemm<0><<<dim3(6 * XJ), 256, 0, stream>>>(
        x, (const unsigned short*)nullptr, perm, t0, slabs, wfrag, bih0, xgA);
    // layer 0 recurrence -> h1buf
    k_recur<0><<<256, 512, 0, stream>>>(
        wfrag + 1 * 196608, bhh0, xgA, Ta, h0s, first, save, h1buf,
        (float*)nullptr, (float*)nullptr, 0);
    // layer 1 input projection (dense h1)
    k_xgemm<1><<<dim3(6 * XJ), 256, 0, stream>>>(
        (const float*)nullptr, h1buf, (const int*)nullptr, 0, slabs,
        wfrag + 2 * 196608, bih1, xgB);
    // layer 1 recurrence -> mean accumulation / output
    k_recur<1><<<256, 512, 0, stream>>>(
        wfrag + 3 * 196608, bhh1, xgB, Ta, h1s, first, save,
        (unsigned short*)nullptr, sums, out, last);
  }
}